// Round 9
// baseline (327.333 us; speedup 1.0000x reference)
//
#include <hip/hip_runtime.h>
#include <hip/hip_bf16.h>
#include <stdint.h>

// ---- problem constants ----
#define D_MODEL 1024
#define SEQ     2048
#define BATCH   4
#define NHEAD   16
#define DKH     64
#define MTOT    (BATCH * SEQ)      // 8192

typedef __bf16 bf16x8 __attribute__((ext_vector_type(8)));
typedef __bf16 bf16x4 __attribute__((ext_vector_type(4)));
typedef float  floatx4 __attribute__((ext_vector_type(4)));

#define GLOAD_LDS16(gp, lp)                                            \
    __builtin_amdgcn_global_load_lds(                                  \
        (const __attribute__((address_space(1))) unsigned int*)(gp),   \
        (__attribute__((address_space(3))) unsigned int*)(lp), 16, 0, 0)

#define MFMA16(a, b, c) __builtin_amdgcn_mfma_f32_16x16x32_bf16(a, b, c, 0, 0, 0)

// ---------------------------------------------------------------------------
// fp32 -> bf16 (exact-size grid)
// ---------------------------------------------------------------------------
__global__ __launch_bounds__(256)
void cvt_x_kernel(const float* __restrict__ src, __bf16* __restrict__ dst)
{
    const int i = (blockIdx.x * 256 + threadIdx.x) * 4;
    floatx4 v = *(const floatx4*)(src + i);
    bf16x4 o;
    o[0] = (__bf16)v[0]; o[1] = (__bf16)v[1]; o[2] = (__bf16)v[2]; o[3] = (__bf16)v[3];
    *(bf16x4*)(dst + i) = o;
}

// fp32 -> bf16: Wq/Wk/Wv stacked into Wcat[3072,1024]. grid (1024, 3).
__global__ __launch_bounds__(256)
void cvt_w3_kernel(const float* __restrict__ Wq, const float* __restrict__ Wk,
                   const float* __restrict__ Wv, __bf16* __restrict__ Wcat)
{
    const int z = blockIdx.y;
    const float* src = (z == 0) ? Wq : ((z == 1) ? Wk : Wv);
    const int i = (blockIdx.x * 256 + threadIdx.x) * 4;
    floatx4 v = *(const floatx4*)(src + i);
    bf16x4 o;
    o[0] = (__bf16)v[0]; o[1] = (__bf16)v[1]; o[2] = (__bf16)v[2]; o[3] = (__bf16)v[3];
    *(bf16x4*)(Wcat + (size_t)z * (D_MODEL * D_MODEL) + i) = o;
}

// ---------------------------------------------------------------------------
// QKV GEMM (pure m97). z = n0>>10: 0->Q [b,h,s,d] PRE-SCALED 1/8, 1->K,
// 2->V^T [b,h,d,s]. grid (24, 64).
// ---------------------------------------------------------------------------
__global__ __launch_bounds__(256)
void qkv_gemm_kernel(const __bf16* __restrict__ xb, const __bf16* __restrict__ Wcat,
                     const float* __restrict__ bq, const float* __restrict__ bk,
                     const float* __restrict__ bv,
                     __bf16* __restrict__ Q, __bf16* __restrict__ K,
                     __bf16* __restrict__ Vt)
{
    __shared__ __align__(16) __bf16 As[128 * 32];
    __shared__ __align__(16) __bf16 Bs[128 * 32];

    const int t    = threadIdx.x;
    const int w    = t >> 6, l = t & 63, quad = l >> 4, r16 = l & 15;
    const int wm   = w & 1, wn = w >> 1;
    const int m0   = blockIdx.y * 128;
    const int n0   = blockIdx.x * 128;
    const int z    = n0 >> 10;
    const float* bias = (z == 0) ? bq : ((z == 1) ? bk : bv);
    __bf16* outQK     = (z == 0) ? Q  : K;
    const float scale = (z == 0) ? 0.125f : 1.0f;

    floatx4 acc[4][4];
#pragma unroll
    for (int i = 0; i < 4; ++i)
#pragma unroll
        for (int j = 0; j < 4; ++j) acc[i][j] = (floatx4){0.f, 0.f, 0.f, 0.f};

    const int c0 = t, c1 = t + 256;
    const __bf16* Ag0 = xb   + (size_t)(m0 + (c0 >> 2)) * 1024 + (c0 & 3) * 8;
    const __bf16* Ag1 = xb   + (size_t)(m0 + (c1 >> 2)) * 1024 + (c1 & 3) * 8;
    const __bf16* Bg0 = Wcat + (size_t)(n0 + (c0 >> 2)) * 1024 + (c0 & 3) * 8;
    const __bf16* Bg1 = Wcat + (size_t)(n0 + (c1 >> 2)) * 1024 + (c1 & 3) * 8;
    unsigned int* lAs = (unsigned int*)As;
    unsigned int* lBs = (unsigned int*)Bs;

    for (int k0 = 0; k0 < 1024; k0 += 32) {
        __syncthreads();
        GLOAD_LDS16(Ag0 + k0, lAs + c0 * 4);
        GLOAD_LDS16(Ag1 + k0, lAs + c1 * 4);
        GLOAD_LDS16(Bg0 + k0, lBs + c0 * 4);
        GLOAD_LDS16(Bg1 + k0, lBs + c1 * 4);
        __syncthreads();

        bf16x8 af[4], bfm[4];
#pragma unroll
        for (int i = 0; i < 4; ++i)
            af[i] = *(const bf16x8*)&As[(wm * 64 + i * 16 + r16) * 32 + quad * 8];
#pragma unroll
        for (int j = 0; j < 4; ++j)
            bfm[j] = *(const bf16x8*)&Bs[(wn * 64 + j * 16 + r16) * 32 + quad * 8];
#pragma unroll
        for (int i = 0; i < 4; ++i)
#pragma unroll
            for (int j = 0; j < 4; ++j)
                acc[i][j] = MFMA16(af[i], bfm[j], acc[i][j]);
    }

#pragma unroll
    for (int i = 0; i < 4; ++i) {
        const int mg = m0 + wm * 64 + i * 16 + quad * 4;
#pragma unroll
        for (int j = 0; j < 4; ++j) {
            const int ng = n0 + wn * 64 + j * 16 + r16;
            const int f = ng & 1023, h = f >> 6, d = f & 63;
            const float bb = bias[f];
#pragma unroll
            for (int r = 0; r < 4; ++r) {
                const int m = mg + r;
                const int b = m >> 11, s = m & 2047;
                const float v = (acc[i][j][r] + bb) * scale;
                if (z == 2)
                    Vt[((size_t)((b * 16 + h) * 64 + d) << 11) + s] = (__bf16)v;
                else
                    outQK[((size_t)(b * 16 + h) << 17) + ((size_t)s << 6) + d] =
                        (__bf16)v;
            }
        }
    }
}

// ---------------------------------------------------------------------------
// Output GEMM (m97 structure, unchanged)
// ---------------------------------------------------------------------------
__global__ __launch_bounds__(256)
void out_gemm_kernel(const __bf16* __restrict__ A, const __bf16* __restrict__ Wob,
                     const float* __restrict__ bo, float* __restrict__ out)
{
    __shared__ __align__(16) __bf16 As[128 * 32];
    __shared__ __align__(16) __bf16 Bs[128 * 32];

    const int t    = threadIdx.x;
    const int w    = t >> 6, l = t & 63, quad = l >> 4, r16 = l & 15;
    const int wm   = w & 1, wn = w >> 1;
    const int m0   = blockIdx.y * 128;
    const int n0   = blockIdx.x * 128;

    floatx4 acc[4][4];
#pragma unroll
    for (int i = 0; i < 4; ++i)
#pragma unroll
        for (int j = 0; j < 4; ++j) acc[i][j] = (floatx4){0.f, 0.f, 0.f, 0.f};

    const int c0 = t, c1 = t + 256;
    const __bf16* Ag0 = A   + (size_t)(m0 + (c0 >> 2)) * 1024 + (c0 & 3) * 8;
    const __bf16* Ag1 = A   + (size_t)(m0 + (c1 >> 2)) * 1024 + (c1 & 3) * 8;
    const __bf16* Bg0 = Wob + (size_t)(n0 + (c0 >> 2)) * 1024 + (c0 & 3) * 8;
    const __bf16* Bg1 = Wob + (size_t)(n0 + (c1 >> 2)) * 1024 + (c1 & 3) * 8;
    unsigned int* lAs = (unsigned int*)As;
    unsigned int* lBs = (unsigned int*)Bs;

    for (int k0 = 0; k0 < 1024; k0 += 32) {
        __syncthreads();
        GLOAD_LDS16(Ag0 + k0, lAs + c0 * 4);
        GLOAD_LDS16(Ag1 + k0, lAs + c1 * 4);
        GLOAD_LDS16(Bg0 + k0, lBs + c0 * 4);
        GLOAD_LDS16(Bg1 + k0, lBs + c1 * 4);
        __syncthreads();

        bf16x8 af[4], bfm[4];
#pragma unroll
        for (int i = 0; i < 4; ++i)
            af[i] = *(const bf16x8*)&As[(wm * 64 + i * 16 + r16) * 32 + quad * 8];
#pragma unroll
        for (int j = 0; j < 4; ++j)
            bfm[j] = *(const bf16x8*)&Bs[(wn * 64 + j * 16 + r16) * 32 + quad * 8];
#pragma unroll
        for (int i = 0; i < 4; ++i)
#pragma unroll
            for (int j = 0; j < 4; ++j)
                acc[i][j] = MFMA16(af[i], bfm[j], acc[i][j]);
    }

#pragma unroll
    for (int i = 0; i < 4; ++i) {
        const int mg = m0 + wm * 64 + i * 16 + quad * 4;
#pragma unroll
        for (int j = 0; j < 4; ++j) {
            const int ng = n0 + wn * 64 + j * 16 + r16;
            const float bb = bo[ng];
#pragma unroll
            for (int r = 0; r < 4; ++r)
                out[(size_t)(mg + r) * 1024 + ng] = acc[i][j][r] + bb;
        }
    }
}

// ---------------------------------------------------------------------------
// Flash attention v5 — k-split chunks (deferred softmax is linear in k).
// grid (24, 64): x<8 -> qt=x, full range [0, 2qt+2) -> OA/lA.
//   x>=8 -> qt=8+((x-8)>>1), chunk c=(x-8)&1, half=qt+1:
//     c=0: kt [0, qt+1)        (provably mask-free, all waves active) -> OA/lA
//     c=1: kt [qt+1, 2qt+2)    (diagonal chunk) -> OB/lB
// Outputs UNNORMALIZED partial O (bf16, [B,H,S,64]) + partial l (fp32).
// Max serial chunk = 16 tiles (was 32) -> balanced concurrency.
// ---------------------------------------------------------------------------
__global__ __launch_bounds__(256)
void attn_kernel(const __bf16* __restrict__ Qg, const __bf16* __restrict__ Kg,
                 const __bf16* __restrict__ Vtg,
                 __bf16* __restrict__ OA, __bf16* __restrict__ OB,
                 float* __restrict__ lA, float* __restrict__ lB)
{
    __shared__ __align__(16) __bf16 Ks[64 * 72];
    __shared__ __align__(16) __bf16 Vt[64 * 72];
    __shared__ __align__(16) __bf16 Ps[4][32 * 72];

    const int t    = threadIdx.x;
    const int w    = t >> 6, l = t & 63, quad = l >> 4, r16 = l & 15;
    const int bh   = blockIdx.y;
    const int xw   = blockIdx.x;

    int qt, kt0, kt1;
    __bf16* obuf; float* lbuf;
    if (xw < 8) {
        qt = xw; kt0 = 0; kt1 = 2 * qt + 2; obuf = OA; lbuf = lA;
    } else {
        qt = 8 + ((xw - 8) >> 1);
        const int c = (xw - 8) & 1, half = qt + 1;
        kt0 = c ? half : 0; kt1 = kt0 + half;
        obuf = c ? OB : OA; lbuf = c ? lB : lA;
    }

    const int q0   = qt * 128;
    const size_t base = (size_t)bh * SEQ * DKH;
    __bf16* Pw = &Ps[w][0];

    bf16x8 qf[2][2];
#pragma unroll
    for (int mi = 0; mi < 2; ++mi) {
        const int row = q0 + w * 32 + mi * 16 + r16;
        qf[mi][0] = *(const bf16x8*)&Qg[base + (size_t)row * 64 + quad * 8];
        qf[mi][1] = *(const bf16x8*)&Qg[base + (size_t)row * 64 + 32 + quad * 8];
    }

    floatx4 o[2][4];
#pragma unroll
    for (int mi = 0; mi < 2; ++mi)
#pragma unroll
        for (int j = 0; j < 4; ++j) o[mi][j] = (floatx4){0.f, 0.f, 0.f, 0.f};
    float lsum[2] = {0.f, 0.f};

    const int wrow0 = q0 + w * 32;
    const int srow  = t >> 3;
    const int sg    = (t & 7) * 8;

    bf16x8 pk[2], pv[2];
#pragma unroll
    for (int it = 0; it < 2; ++it) {
        const int row = it * 32 + srow;
        pk[it] = *(const bf16x8*)&Kg[base + (size_t)(kt0 * 64 + row) * 64 + sg];
        pv[it] = *(const bf16x8*)&Vtg[base + (size_t)row * 2048 + kt0 * 64 + sg];
    }

    for (int kt = kt0; kt < kt1; ++kt) {
        __syncthreads();
#pragma unroll
        for (int it = 0; it < 2; ++it) {
            const int row = it * 32 + srow;
            *(bf16x8*)&Ks[row * 72 + sg] = pk[it];
            *(bf16x8*)&Vt[row * 72 + sg] = pv[it];
        }
        __syncthreads();
        if (kt + 1 < kt1) {
#pragma unroll
            for (int it = 0; it < 2; ++it) {
                const int row = it * 32 + srow;
                pk[it] = *(const bf16x8*)&Kg[base + (size_t)((kt + 1) * 64 + row) * 64 + sg];
                pv[it] = *(const bf16x8*)&Vtg[base + (size_t)row * 2048 + (kt + 1) * 64 + sg];
            }
        }

        const bool active = (kt * 64 <= wrow0 + 31);   // wave-uniform
        if (active) {
            bf16x8 kf[4][2];
#pragma unroll
            for (int j = 0; j < 4; ++j) {
                kf[j][0] = *(const bf16x8*)&Ks[(j * 16 + r16) * 72 + quad * 8];
                kf[j][1] = *(const bf16x8*)&Ks[(j * 16 + r16) * 72 + 32 + quad * 8];
            }
#pragma unroll
            for (int mi = 0; mi < 2; ++mi) {
                const int rmin = wrow0 + mi * 16;
                if (kt * 64 > rmin + 15) continue;
                const int qg = rmin + r16;
#pragma unroll
                for (int j = 0; j < 4; ++j) {
                    floatx4 z = (floatx4){0.f, 0.f, 0.f, 0.f};
                    z = MFMA16(kf[j][0], qf[mi][0], z);
                    z = MFMA16(kf[j][1], qf[mi][1], z);
                    bf16x4 p4;
                    float ls = 0.f;
#pragma unroll
                    for (int r = 0; r < 4; ++r) {
                        const int kg = kt * 64 + j * 16 + quad * 4 + r;
                        float p = 0.f;
                        if (kg <= qg)
                            p = __expf(fminf(z[r], 70.f));
                        ls += p;
                        p4[r] = (__bf16)p;
                    }
                    lsum[mi] += ls;
                    *(bf16x4*)&Pw[(mi * 16 + r16) * 72 + j * 16 + quad * 4] = p4;
                }
            }
            __asm__ __volatile__("s_waitcnt lgkmcnt(0)" ::: "memory");

            bf16x8 vf[4][2];
#pragma unroll
            for (int jd = 0; jd < 4; ++jd) {
                vf[jd][0] = *(const bf16x8*)&Vt[(jd * 16 + r16) * 72 + quad * 8];
                vf[jd][1] = *(const bf16x8*)&Vt[(jd * 16 + r16) * 72 + 32 + quad * 8];
            }
#pragma unroll
            for (int mi = 0; mi < 2; ++mi) {
                if (kt * 64 > wrow0 + mi * 16 + 15) continue;
                bf16x8 pf0 = *(const bf16x8*)&Pw[(mi * 16 + r16) * 72 + quad * 8];
                bf16x8 pf1 = *(const bf16x8*)&Pw[(mi * 16 + r16) * 72 + 32 + quad * 8];
#pragma unroll
                for (int jd = 0; jd < 4; ++jd) {
                    o[mi][jd] = MFMA16(pf0, vf[jd][0], o[mi][jd]);
                    o[mi][jd] = MFMA16(pf1, vf[jd][1], o[mi][jd]);
                }
            }
        }
    }

    // reduce l across quad replicas (all lanes end with full sum for col r16)
    float lred[2];
#pragma unroll
    for (int mi = 0; mi < 2; ++mi) {
        float v = lsum[mi];
        v += __shfl_xor(v, 16, 64);
        v += __shfl_xor(v, 32, 64);
        lred[mi] = v;
    }

    // write UNNORMALIZED partial O [B,H,S,64] + l (quad-0 lanes)
#pragma unroll
    for (int mi = 0; mi < 2; ++mi) {
        if (quad == 0)
            lbuf[bh * SEQ + wrow0 + mi * 16 + r16] = lred[mi];
#pragma unroll
        for (int r = 0; r < 4; ++r) {
            const int row = wrow0 + mi * 16 + quad * 4 + r;
#pragma unroll
            for (int jd = 0; jd < 4; ++jd) {
                const int d = jd * 16 + r16;
                obuf[base + (size_t)row * 64 + d] = (__bf16)o[mi][jd][r];
            }
        }
    }
}

// ---------------------------------------------------------------------------
// Merge partials + normalize + permute to [B,S,H*64] bf16.
// qt(s) < 8: O = OA/lA ; else O = (OA+OB)/(lA+lB). 8 elems/thread.
// ---------------------------------------------------------------------------
__global__ __launch_bounds__(256)
void norm_kernel(const __bf16* __restrict__ OA, const __bf16* __restrict__ OB,
                 const float* __restrict__ lA, const float* __restrict__ lB,
                 __bf16* __restrict__ Ab)
{
    const int gid = blockIdx.x * 256 + threadIdx.x;   // 1,048,576 threads
    const int row = gid >> 3;                          // [bh*2048 + s]
    const int d0  = (gid & 7) * 8;
    const int s   = row & 2047, bh = row >> 11;
    const size_t src = (size_t)row * 64 + d0;

    float lv = lA[row];
    bf16x8 a = *(const bf16x8*)&OA[src];
    float acc[8];
#pragma unroll
    for (int e = 0; e < 8; ++e) acc[e] = (float)a[e];
    if ((s >> 7) >= 8) {
        lv += lB[row];
        bf16x8 b = *(const bf16x8*)&OB[src];
#pragma unroll
        for (int e = 0; e < 8; ++e) acc[e] += (float)b[e];
    }
    const float inv = 1.f / lv;
    bf16x8 o;
#pragma unroll
    for (int e = 0; e < 8; ++e) o[e] = (__bf16)(acc[e] * inv);
    const int b = bh >> 4, h = bh & 15;
    *(bf16x8*)&Ab[((size_t)(b * SEQ + s) << 10) + h * 64 + d0] = o;
}

// ---------------------------------------------------------------------------
extern "C" void kernel_launch(void* const* d_in, const int* in_sizes, int n_in,
                              void* d_out, int out_size, void* d_ws, size_t ws_size,
                              hipStream_t stream)
{
    (void)in_sizes; (void)n_in; (void)out_size; (void)ws_size;
    const float* x  = (const float*)d_in[0];
    const float* Wq = (const float*)d_in[1];
    const float* bq = (const float*)d_in[2];
    const float* Wk = (const float*)d_in[3];
    const float* bk = (const float*)d_in[4];
    const float* Wv = (const float*)d_in[5];
    const float* bv = (const float*)d_in[6];
    const float* Wo = (const float*)d_in[7];
    const float* bo = (const float*)d_in[8];
    float* out = (float*)d_out;

    const size_t n_elem = (size_t)MTOT * D_MODEL;       // 8388608
    const int    w_n    = D_MODEL * D_MODEL;            // 1048576
    // d_out (32MB used): [Qb 16MB][xb 16MB]; xb becomes OB after qkv.
    __bf16* Qb = (__bf16*)d_out;
    __bf16* xb = Qb + n_elem;
    __bf16* OB = xb;
    // ws (>=64MB proven by round 1; we use 49MB):
    //   [Kb 16][Vtb 16][OA 16][lA 0.5][lB 0.5]
    __bf16* Kb  = (__bf16*)d_ws;
    __bf16* Vtb = Kb + n_elem;
    __bf16* OA  = Vtb + n_elem;
    float*  lA  = (float*)(OA + n_elem);
    float*  lB  = lA + 64 * SEQ;
    __bf16* Wcat = OA;    // consumed by qkv before attn writes OA
    __bf16* Wob  = Vtb;   // V^T dead after attn
    __bf16* Ab   = Kb;    // K dead after attn

    cvt_x_kernel<<<MTOT * D_MODEL / 1024, 256, 0, stream>>>(x, xb);
    cvt_w3_kernel<<<dim3(w_n / 1024, 3), 256, 0, stream>>>(Wq, Wk, Wv, Wcat);
    qkv_gemm_kernel<<<dim3(24, 64), 256, 0, stream>>>(xb, Wcat, bq, bk, bv,
                                                      Qb, Kb, Vtb);
    attn_kernel<<<dim3(24, 64), 256, 0, stream>>>(Qb, Kb, Vtb, OA, OB, lA, lB);
    cvt_x_kernel<<<w_n / 1024, 256, 0, stream>>>(Wo, Wob);
    norm_kernel<<<4096, 256, 0, stream>>>(OA, OB, lA, lB, Ab);
    out_gemm_kernel<<<dim3(8, 64), 256, 0, stream>>>(Ab, Wob, bo, out);
}

// Round 10
// 325.504 us; speedup vs baseline: 1.0056x; 1.0056x over previous
//
#include <hip/hip_runtime.h>
#include <hip/hip_bf16.h>
#include <stdint.h>

// ---- problem constants ----
#define D_MODEL 1024
#define SEQ     2048
#define BATCH   4
#define NHEAD   16
#define DKH     64
#define MTOT    (BATCH * SEQ)      // 8192

typedef __bf16 bf16x8 __attribute__((ext_vector_type(8)));
typedef __bf16 bf16x4 __attribute__((ext_vector_type(4)));
typedef float  floatx4 __attribute__((ext_vector_type(4)));
typedef short  s16x4   __attribute__((ext_vector_type(4)));

#define GLOAD_LDS16(gp, lp)                                            \
    __builtin_amdgcn_global_load_lds(                                  \
        (const __attribute__((address_space(1))) unsigned int*)(gp),   \
        (__attribute__((address_space(3))) unsigned int*)(lp), 16, 0, 0)

#define MFMA16(a, b, c)  __builtin_amdgcn_mfma_f32_16x16x32_bf16(a, b, c, 0, 0, 0)
#define MFMA1K(a, b, c)  __builtin_amdgcn_mfma_f32_16x16x16bf16_1k(a, b, c, 0, 0, 0)

__device__ __forceinline__ s16x4 packbf4(floatx4 v) {
    bf16x4 t;
    t[0] = (__bf16)v[0]; t[1] = (__bf16)v[1];
    t[2] = (__bf16)v[2]; t[3] = (__bf16)v[3];
    return __builtin_bit_cast(s16x4, t);
}

// ---------------------------------------------------------------------------
// fp32 -> bf16 (exact-size grid)
// ---------------------------------------------------------------------------
__global__ __launch_bounds__(256)
void cvt_x_kernel(const float* __restrict__ src, __bf16* __restrict__ dst)
{
    const int i = (blockIdx.x * 256 + threadIdx.x) * 4;
    floatx4 v = *(const floatx4*)(src + i);
    bf16x4 o;
    o[0] = (__bf16)v[0]; o[1] = (__bf16)v[1]; o[2] = (__bf16)v[2]; o[3] = (__bf16)v[3];
    *(bf16x4*)(dst + i) = o;
}

// fp32 -> bf16: Wq/Wk/Wv stacked into Wcat[3072,1024]. grid (1024, 3).
__global__ __launch_bounds__(256)
void cvt_w3_kernel(const float* __restrict__ Wq, const float* __restrict__ Wk,
                   const float* __restrict__ Wv, __bf16* __restrict__ Wcat)
{
    const int z = blockIdx.y;
    const float* src = (z == 0) ? Wq : ((z == 1) ? Wk : Wv);
    const int i = (blockIdx.x * 256 + threadIdx.x) * 4;
    floatx4 v = *(const floatx4*)(src + i);
    bf16x4 o;
    o[0] = (__bf16)v[0]; o[1] = (__bf16)v[1]; o[2] = (__bf16)v[2]; o[3] = (__bf16)v[3];
    *(bf16x4*)(Wcat + (size_t)z * (D_MODEL * D_MODEL) + i) = o;
}

// ---------------------------------------------------------------------------
// QKV GEMM (pure m97). z = n0>>10: 0->Q [b,h,s,d] PRE-SCALED 1/8, 1->K,
// 2->V^T [b,h,d,s]. grid (24, 64).
// ---------------------------------------------------------------------------
__global__ __launch_bounds__(256)
void qkv_gemm_kernel(const __bf16* __restrict__ xb, const __bf16* __restrict__ Wcat,
                     const float* __restrict__ bq, const float* __restrict__ bk,
                     const float* __restrict__ bv,
                     __bf16* __restrict__ Q, __bf16* __restrict__ K,
                     __bf16* __restrict__ Vt)
{
    __shared__ __align__(16) __bf16 As[128 * 32];
    __shared__ __align__(16) __bf16 Bs[128 * 32];

    const int t    = threadIdx.x;
    const int w    = t >> 6, l = t & 63, quad = l >> 4, r16 = l & 15;
    const int wm   = w & 1, wn = w >> 1;
    const int m0   = blockIdx.y * 128;
    const int n0   = blockIdx.x * 128;
    const int z    = n0 >> 10;
    const float* bias = (z == 0) ? bq : ((z == 1) ? bk : bv);
    __bf16* outQK     = (z == 0) ? Q  : K;
    const float scale = (z == 0) ? 0.125f : 1.0f;

    floatx4 acc[4][4];
#pragma unroll
    for (int i = 0; i < 4; ++i)
#pragma unroll
        for (int j = 0; j < 4; ++j) acc[i][j] = (floatx4){0.f, 0.f, 0.f, 0.f};

    const int c0 = t, c1 = t + 256;
    const __bf16* Ag0 = xb   + (size_t)(m0 + (c0 >> 2)) * 1024 + (c0 & 3) * 8;
    const __bf16* Ag1 = xb   + (size_t)(m0 + (c1 >> 2)) * 1024 + (c1 & 3) * 8;
    const __bf16* Bg0 = Wcat + (size_t)(n0 + (c0 >> 2)) * 1024 + (c0 & 3) * 8;
    const __bf16* Bg1 = Wcat + (size_t)(n0 + (c1 >> 2)) * 1024 + (c1 & 3) * 8;
    unsigned int* lAs = (unsigned int*)As;
    unsigned int* lBs = (unsigned int*)Bs;

    for (int k0 = 0; k0 < 1024; k0 += 32) {
        __syncthreads();
        GLOAD_LDS16(Ag0 + k0, lAs + c0 * 4);
        GLOAD_LDS16(Ag1 + k0, lAs + c1 * 4);
        GLOAD_LDS16(Bg0 + k0, lBs + c0 * 4);
        GLOAD_LDS16(Bg1 + k0, lBs + c1 * 4);
        __syncthreads();

        bf16x8 af[4], bfm[4];
#pragma unroll
        for (int i = 0; i < 4; ++i)
            af[i] = *(const bf16x8*)&As[(wm * 64 + i * 16 + r16) * 32 + quad * 8];
#pragma unroll
        for (int j = 0; j < 4; ++j)
            bfm[j] = *(const bf16x8*)&Bs[(wn * 64 + j * 16 + r16) * 32 + quad * 8];
#pragma unroll
        for (int i = 0; i < 4; ++i)
#pragma unroll
            for (int j = 0; j < 4; ++j)
                acc[i][j] = MFMA16(af[i], bfm[j], acc[i][j]);
    }

#pragma unroll
    for (int i = 0; i < 4; ++i) {
        const int mg = m0 + wm * 64 + i * 16 + quad * 4;
#pragma unroll
        for (int j = 0; j < 4; ++j) {
            const int ng = n0 + wn * 64 + j * 16 + r16;
            const int f = ng & 1023, h = f >> 6, d = f & 63;
            const float bb = bias[f];
#pragma unroll
            for (int r = 0; r < 4; ++r) {
                const int m = mg + r;
                const int b = m >> 11, s = m & 2047;
                const float v = (acc[i][j][r] + bb) * scale;
                if (z == 2)
                    Vt[((size_t)((b * 16 + h) * 64 + d) << 11) + s] = (__bf16)v;
                else
                    outQK[((size_t)(b * 16 + h) << 17) + ((size_t)s << 6) + d] =
                        (__bf16)v;
            }
        }
    }
}

// ---------------------------------------------------------------------------
// Output GEMM (m97 structure, unchanged)
// ---------------------------------------------------------------------------
__global__ __launch_bounds__(256)
void out_gemm_kernel(const __bf16* __restrict__ A, const __bf16* __restrict__ Wob,
                     const float* __restrict__ bo, float* __restrict__ out)
{
    __shared__ __align__(16) __bf16 As[128 * 32];
    __shared__ __align__(16) __bf16 Bs[128 * 32];

    const int t    = threadIdx.x;
    const int w    = t >> 6, l = t & 63, quad = l >> 4, r16 = l & 15;
    const int wm   = w & 1, wn = w >> 1;
    const int m0   = blockIdx.y * 128;
    const int n0   = blockIdx.x * 128;

    floatx4 acc[4][4];
#pragma unroll
    for (int i = 0; i < 4; ++i)
#pragma unroll
        for (int j = 0; j < 4; ++j) acc[i][j] = (floatx4){0.f, 0.f, 0.f, 0.f};

    const int c0 = t, c1 = t + 256;
    const __bf16* Ag0 = A   + (size_t)(m0 + (c0 >> 2)) * 1024 + (c0 & 3) * 8;
    const __bf16* Ag1 = A   + (size_t)(m0 + (c1 >> 2)) * 1024 + (c1 & 3) * 8;
    const __bf16* Bg0 = Wob + (size_t)(n0 + (c0 >> 2)) * 1024 + (c0 & 3) * 8;
    const __bf16* Bg1 = Wob + (size_t)(n0 + (c1 >> 2)) * 1024 + (c1 & 3) * 8;
    unsigned int* lAs = (unsigned int*)As;
    unsigned int* lBs = (unsigned int*)Bs;

    for (int k0 = 0; k0 < 1024; k0 += 32) {
        __syncthreads();
        GLOAD_LDS16(Ag0 + k0, lAs + c0 * 4);
        GLOAD_LDS16(Ag1 + k0, lAs + c1 * 4);
        GLOAD_LDS16(Bg0 + k0, lBs + c0 * 4);
        GLOAD_LDS16(Bg1 + k0, lBs + c1 * 4);
        __syncthreads();

        bf16x8 af[4], bfm[4];
#pragma unroll
        for (int i = 0; i < 4; ++i)
            af[i] = *(const bf16x8*)&As[(wm * 64 + i * 16 + r16) * 32 + quad * 8];
#pragma unroll
        for (int j = 0; j < 4; ++j)
            bfm[j] = *(const bf16x8*)&Bs[(wn * 64 + j * 16 + r16) * 32 + quad * 8];
#pragma unroll
        for (int i = 0; i < 4; ++i)
#pragma unroll
            for (int j = 0; j < 4; ++j)
                acc[i][j] = MFMA16(af[i], bfm[j], acc[i][j]);
    }

#pragma unroll
    for (int i = 0; i < 4; ++i) {
        const int mg = m0 + wm * 64 + i * 16 + quad * 4;
#pragma unroll
        for (int j = 0; j < 4; ++j) {
            const int ng = n0 + wn * 64 + j * 16 + r16;
            const float bb = bo[ng];
#pragma unroll
            for (int r = 0; r < 4; ++r)
                out[(size_t)(mg + r) * 1024 + ng] = acc[i][j][r] + bb;
        }
    }
}

// ---------------------------------------------------------------------------
// Flash attention v6. Q (pre-scaled 1/8), K in [B,H,S,64]; V^T [B,H,64,S].
// grid (16, 64), round-8 balance swizzle. 128 q-rows/block, 4 waves x 32.
//
// Round-10 redesign (chain-latency driven):
//  * P never touches LDS: S^T C-layout (lane: k=j*16+quad*4+r, q=r16) IS the
//    B-operand layout of mfma_f32_16x16x16bf16_1k (B[k=quad*4+i][n=r16]).
//    PV = mfma(V^T-frag A[m=d][k], P-reg B, o). Output is O^T-layout
//    (lane: d=jd*16+quad*4+r, q=r16) -> l is lane-local at epilogue.
//  * True LDS double-buffer, ONE barrier per k-tile (write kt+1 into buf p^1
//    while computing buf p; global prefetch kt+2 in regs).
//  * Single full-range pass per q-tile (no k-split, no norm kernel).
// ---------------------------------------------------------------------------
__global__ __launch_bounds__(256)
void attn_kernel(const __bf16* __restrict__ Qg, const __bf16* __restrict__ Kg,
                 const __bf16* __restrict__ Vtg, __bf16* __restrict__ Ab)
{
    __shared__ __align__(16) __bf16 Ks[2][64 * 72];
    __shared__ __align__(16) __bf16 Vt[2][64 * 72];

    const int t    = threadIdx.x;
    const int w    = t >> 6, l = t & 63, quad = l >> 4, r16 = l & 15;
    const int bh   = blockIdx.y;
    // co-resident blocks (linear ids 256 apart: same x, y+16k) alternate
    // qt <-> 15-qt so every CU gets equal total k-tiles.
    const int qt   = ((blockIdx.y >> 4) & 1) ? (15 - (int)blockIdx.x)
                                             : (int)blockIdx.x;
    const int q0   = qt * 128;
    const size_t base = (size_t)bh * SEQ * DKH;

    // Q B-frags for S^T = K·Q^T
    bf16x8 qf[2][2];
#pragma unroll
    for (int mi = 0; mi < 2; ++mi) {
        const int row = q0 + w * 32 + mi * 16 + r16;
        qf[mi][0] = *(const bf16x8*)&Qg[base + (size_t)row * 64 + quad * 8];
        qf[mi][1] = *(const bf16x8*)&Qg[base + (size_t)row * 64 + 32 + quad * 8];
    }

    floatx4 o[2][4];      // O^T: o[mi][jd][r] = O[d=jd*16+quad*4+r][q=...r16]
#pragma unroll
    for (int mi = 0; mi < 2; ++mi)
#pragma unroll
        for (int j = 0; j < 4; ++j) o[mi][j] = (floatx4){0.f, 0.f, 0.f, 0.f};
    float lsum[2] = {0.f, 0.f};

    const int wrow0 = q0 + w * 32;
    const int nkt   = 2 * qt + 2;
    const int srow  = t >> 3;            // staging: 8 lanes/row, coalesced
    const int sg    = (t & 7) * 8;

    bf16x8 pk[2], pv[2];
    // stage kt=0 into buf 0
#pragma unroll
    for (int it = 0; it < 2; ++it) {
        const int row = it * 32 + srow;
        pk[it] = *(const bf16x8*)&Kg[base + (size_t)row * 64 + sg];
        pv[it] = *(const bf16x8*)&Vtg[base + (size_t)row * 2048 + sg];
        *(bf16x8*)&Ks[0][row * 72 + sg] = pk[it];
        *(bf16x8*)&Vt[0][row * 72 + sg] = pv[it];
    }
    // prefetch kt=1 (nkt >= 2 always)
#pragma unroll
    for (int it = 0; it < 2; ++it) {
        const int row = it * 32 + srow;
        pk[it] = *(const bf16x8*)&Kg[base + (size_t)(64 + row) * 64 + sg];
        pv[it] = *(const bf16x8*)&Vtg[base + (size_t)row * 2048 + 64 + sg];
    }
    __syncthreads();

    for (int kt = 0; kt < nkt; ++kt) {
        const int p = kt & 1;
        if (kt + 1 < nkt) {              // write staged regs (tile kt+1)
#pragma unroll
            for (int it = 0; it < 2; ++it) {
                const int row = it * 32 + srow;
                *(bf16x8*)&Ks[p ^ 1][row * 72 + sg] = pk[it];
                *(bf16x8*)&Vt[p ^ 1][row * 72 + sg] = pv[it];
            }
        }
        if (kt + 2 < nkt) {              // prefetch tile kt+2
#pragma unroll
            for (int it = 0; it < 2; ++it) {
                const int row = it * 32 + srow;
                pk[it] = *(const bf16x8*)&Kg[base + (size_t)((kt + 2) * 64 + row) * 64 + sg];
                pv[it] = *(const bf16x8*)&Vtg[base + (size_t)row * 2048 + (kt + 2) * 64 + sg];
            }
        }

        const bool active = (kt * 64 <= wrow0 + 31);   // wave-uniform
        if (active) {
            const __bf16* Kp = &Ks[p][0];
            const __bf16* Vp = &Vt[p][0];
            // S^T = K·Q^T
            floatx4 sc[2][4];
#pragma unroll
            for (int j = 0; j < 4; ++j) {
                bf16x8 kf0 = *(const bf16x8*)&Kp[(j * 16 + r16) * 72 + quad * 8];
                bf16x8 kf1 = *(const bf16x8*)&Kp[(j * 16 + r16) * 72 + 32 + quad * 8];
                floatx4 z0 = (floatx4){0.f, 0.f, 0.f, 0.f};
                z0 = MFMA16(kf0, qf[0][0], z0);
                z0 = MFMA16(kf1, qf[0][1], z0);
                sc[0][j] = z0;
                floatx4 z1 = (floatx4){0.f, 0.f, 0.f, 0.f};
                z1 = MFMA16(kf0, qf[1][0], z1);
                z1 = MFMA16(kf1, qf[1][1], z1);
                sc[1][j] = z1;
            }
            // deferred softmax: exp only (mask on diagonal tiles)
#pragma unroll
            for (int mi = 0; mi < 2; ++mi) {
                const int rmin = wrow0 + mi * 16;
                if (kt * 64 + 63 <= rmin) {            // fully unmasked
                    float ls = 0.f;
#pragma unroll
                    for (int j = 0; j < 4; ++j)
#pragma unroll
                        for (int r = 0; r < 4; ++r) {
                            const float pv_ = __expf(fminf(sc[mi][j][r], 70.f));
                            sc[mi][j][r] = pv_;
                            ls += pv_;
                        }
                    lsum[mi] += ls;
                } else {                               // diagonal tile
                    const int qg = rmin + r16;
                    float ls = 0.f;
#pragma unroll
                    for (int j = 0; j < 4; ++j)
#pragma unroll
                        for (int r = 0; r < 4; ++r) {
                            const int kg = kt * 64 + j * 16 + quad * 4 + r;
                            float pv_ = 0.f;
                            if (kg <= qg)
                                pv_ = __expf(fminf(sc[mi][j][r], 70.f));
                            sc[mi][j][r] = pv_;
                            ls += pv_;
                        }
                    lsum[mi] += ls;
                }
            }
            // PV: O^T += V^T-frag (A) x P-reg (B), K=16 MFMA
#pragma unroll
            for (int j = 0; j < 4; ++j) {
                const s16x4 bP0 = packbf4(sc[0][j]);
                const s16x4 bP1 = packbf4(sc[1][j]);
#pragma unroll
                for (int jd = 0; jd < 4; ++jd) {
                    const s16x4 va = *(const s16x4*)
                        &Vp[(jd * 16 + r16) * 72 + j * 16 + quad * 4];
                    o[0][jd] = MFMA1K(va, bP0, o[0][jd]);
                    o[1][jd] = MFMA1K(va, bP1, o[1][jd]);
                }
            }
        }
        __syncthreads();                 // one barrier per tile
    }

    // l for this lane's column q = wrow0+mi*16+r16: reduce across quads
    float lred[2];
#pragma unroll
    for (int mi = 0; mi < 2; ++mi) {
        float v = lsum[mi];
        v += __shfl_xor(v, 16, 64);
        v += __shfl_xor(v, 32, 64);
        lred[mi] = v;
    }

    // epilogue: O^T-layout -> Ab [B,S,H*64]; lane writes 4 consecutive d (b64)
    const int b = bh >> 4, h = bh & 15;
#pragma unroll
    for (int mi = 0; mi < 2; ++mi) {
        const float inv = 1.f / lred[mi];
        const int qrow = wrow0 + mi * 16 + r16;
        const size_t rbase = ((size_t)(b * SEQ + qrow) << 10) + h * 64;
#pragma unroll
        for (int jd = 0; jd < 4; ++jd) {
            bf16x4 ov;
#pragma unroll
            for (int r = 0; r < 4; ++r) ov[r] = (__bf16)(o[mi][jd][r] * inv);
            *(bf16x4*)&Ab[rbase + jd * 16 + quad * 4] = ov;
        }
    }
}

// ---------------------------------------------------------------------------
extern "C" void kernel_launch(void* const* d_in, const int* in_sizes, int n_in,
                              void* d_out, int out_size, void* d_ws, size_t ws_size,
                              hipStream_t stream)
{
    (void)in_sizes; (void)n_in; (void)out_size; (void)ws_size;
    const float* x  = (const float*)d_in[0];
    const float* Wq = (const float*)d_in[1];
    const float* bq = (const float*)d_in[2];
    const float* Wk = (const float*)d_in[3];
    const float* bk = (const float*)d_in[4];
    const float* Wv = (const float*)d_in[5];
    const float* bv = (const float*)d_in[6];
    const float* Wo = (const float*)d_in[7];
    const float* bo = (const float*)d_in[8];
    float* out = (float*)d_out;

    const size_t n_elem = (size_t)MTOT * D_MODEL;       // 8388608
    const int    w_n    = D_MODEL * D_MODEL;            // 1048576
    // d_out (32MB used): [Qb bf16 16MB][xb bf16 16MB].
    __bf16* Qb = (__bf16*)d_out;
    __bf16* xb = Qb + n_elem;
    // ws (48MB): [Kb][Vtb][Ab]. Wcat overlays Ab (consumed by qkv before attn
    // writes Ab); Wob overlays dead-after-attn Kb.
    __bf16* Kb   = (__bf16*)d_ws;
    __bf16* Vtb  = Kb + n_elem;
    __bf16* Ab   = Vtb + n_elem;
    __bf16* Wcat = Ab;
    __bf16* Wob  = Kb;

    cvt_x_kernel<<<MTOT * D_MODEL / 1024, 256, 0, stream>>>(x, xb);
    cvt_w3_kernel<<<dim3(w_n / 1024, 3), 256, 0, stream>>>(Wq, Wk, Wv, Wcat);
    qkv_gemm_kernel<<<dim3(24, 64), 256, 0, stream>>>(xb, Wcat, bq, bk, bv,
                                                      Qb, Kb, Vtb);
    attn_kernel<<<dim3(16, 64), 256, 0, stream>>>(Qb, Kb, Vtb, Ab);
    cvt_x_kernel<<<w_n / 1024, 256, 0, stream>>>(Wo, Wob);
    out_gemm_kernel<<<dim3(8, 64), 256, 0, stream>>>(Ab, Wob, bo, out);
}